// Round 1
// baseline (3802.121 us; speedup 1.0000x reference)
//
#include <hip/hip_runtime.h>

#define DDIM 128
#define HDIM 256
#define BQ   4
#define NN   4096
#define RTOT (BQ*NN)

#define SA 268   // padded LDS row stride (floats) for 256-wide tiles (16B aligned, low-conflict)

// ---------------- fused sim (K K^T) + per-row top-8 ----------------
// grid 256 (XCD-swizzled: batch b -> 2 XCDs), block 256, dyn LDS 2*64*SA*4 = 137,216 B
__global__ __launch_bounds__(256, 1)
void sim_topk_kernel(const float* __restrict__ keys, int* __restrict__ idxout) {
    extern __shared__ float smem[];
    float* As = smem;            // [64][SA] row tile (staged once)
    float* Bs = smem + 64 * SA;  // [64][SA] col tile (per chunk)

    int id   = blockIdx.x;
    int b    = (id & 7) >> 1;                  // batch -> XCD pair (assumes id%8 round-robin; perf-only)
    int tile = ((id >> 3) << 1) | (id & 1);
    const float* kb = keys + (size_t)b * NN * HDIM;
    int rowbase = tile * 64;
    int tid = threadIdx.x;

    // stage A rows once
    for (int i = tid; i < 64 * 64; i += 256) {
        int r = i >> 6, c = i & 63;
        *(float4*)&As[r * SA + c * 4] =
            *(const float4*)&kb[(size_t)(rowbase + r) * HDIM + c * 4];
    }

    int ty = tid >> 4, tx = tid & 15;   // rows: ty+16i, cols: tx+16j (strided -> low bank conflict)

    float tv[4][8]; int tix[4][8];
#pragma unroll
    for (int i = 0; i < 4; ++i)
#pragma unroll
        for (int s = 0; s < 8; ++s) { tv[i][s] = -1e30f; tix[i][s] = 0x7fffffff; }

    for (int chunk = 0; chunk < 64; ++chunk) {
        __syncthreads();   // protect Bs from previous iteration's readers
        for (int i = tid; i < 64 * 64; i += 256) {
            int r = i >> 6, c = i & 63;
            *(float4*)&Bs[r * SA + c * 4] =
                *(const float4*)&kb[(size_t)(chunk * 64 + r) * HDIM + c * 4];
        }
        __syncthreads();

        float acc[4][4];
#pragma unroll
        for (int i = 0; i < 4; ++i)
#pragma unroll
            for (int j = 0; j < 4; ++j) acc[i][j] = 0.f;

#pragma unroll 2
        for (int k = 0; k < HDIM; k += 4) {
            float av[4][4], bv[4][4];
#pragma unroll
            for (int i = 0; i < 4; ++i) {
                float4 t = *(const float4*)&As[(ty + 16 * i) * SA + k];
                av[i][0] = t.x; av[i][1] = t.y; av[i][2] = t.z; av[i][3] = t.w;
            }
#pragma unroll
            for (int j = 0; j < 4; ++j) {
                float4 t = *(const float4*)&Bs[(tx + 16 * j) * SA + k];
                bv[j][0] = t.x; bv[j][1] = t.y; bv[j][2] = t.z; bv[j][3] = t.w;
            }
#pragma unroll
            for (int i = 0; i < 4; ++i)
#pragma unroll
                for (int j = 0; j < 4; ++j) {
                    acc[i][j] += av[i][0] * bv[j][0];
                    acc[i][j] += av[i][1] * bv[j][1];
                    acc[i][j] += av[i][2] * bv[j][2];
                    acc[i][j] += av[i][3] * bv[j][3];
                }
        }

        // per-thread running top-8 (columns scanned in ascending index; strict > keeps lowest index on ties)
#pragma unroll
        for (int i = 0; i < 4; ++i)
#pragma unroll
            for (int j = 0; j < 4; ++j) {
                float v = acc[i][j];
                int col = chunk * 64 + tx + 16 * j;
                if (v > tv[i][7]) {
                    tv[i][7] = v; tix[i][7] = col;
#pragma unroll
                    for (int s = 7; s >= 1; --s) {
                        if (tv[i][s] > tv[i][s - 1]) {
                            float a0 = tv[i][s]; tv[i][s] = tv[i][s - 1]; tv[i][s - 1] = a0;
                            int   c0 = tix[i][s]; tix[i][s] = tix[i][s - 1]; tix[i][s - 1] = c0;
                        }
                    }
                }
            }
    }

    // merge 16 per-thread top-8 lists per row (reuse Bs)
    __syncthreads();
    float* cv = Bs;                       // [64][132]
    int*   ci = (int*)(Bs + 64 * 132);    // [64][132]
#pragma unroll
    for (int i = 0; i < 4; ++i)
#pragma unroll
        for (int s = 0; s < 8; ++s) {
            int r = ty + 16 * i;
            cv[r * 132 + tx * 8 + s] = tv[i][s];
            ci[r * 132 + tx * 8 + s] = tix[i][s];
        }
    __syncthreads();
    if (tid < 64) {
        float fv[8]; int fi[8];
#pragma unroll
        for (int s = 0; s < 8; ++s) { fv[s] = -1e30f; fi[s] = 0x7fffffff; }
        for (int s = 0; s < 128; ++s) {
            float v = cv[tid * 132 + s];
            int   ix = ci[tid * 132 + s];
            bool ins = (v > fv[7]) || ((v == fv[7]) && (ix < fi[7]));   // lexicographic: ties -> lower index
            if (ins) {
                fv[7] = v; fi[7] = ix;
#pragma unroll
                for (int t = 7; t >= 1; --t) {
                    bool sw = (fv[t] > fv[t - 1]) || ((fv[t] == fv[t - 1]) && (fi[t] < fi[t - 1]));
                    if (sw) {
                        float a0 = fv[t]; fv[t] = fv[t - 1]; fv[t - 1] = a0;
                        int   c0 = fi[t]; fi[t] = fi[t - 1]; fi[t - 1] = c0;
                    }
                }
            }
        }
        size_t base = ((size_t)b * NN + rowbase + tid) * 8;
#pragma unroll
        for (int s = 0; s < 8; ++s) idxout[base + s] = fi[s];
    }
}

// ---------------- keys projection GEMM: out = A(Rx128) @ W(128x256) + bias ----------------
// grid R/32, block 256
__global__ __launch_bounds__(256, 2)
void gemm_d_h(const float* __restrict__ A, const float* __restrict__ W,
              const float* __restrict__ bias, float* __restrict__ out) {
    __shared__ float As[32 * 132];
    int tid = threadIdx.x;
    size_t rowbase = (size_t)blockIdx.x * 32;
    for (int i = tid; i < 32 * 32; i += 256) {
        int r = i >> 5, q = i & 31;
        *(float4*)&As[r * 132 + q * 4] = *(const float4*)&A[(rowbase + r) * DDIM + q * 4];
    }
    __syncthreads();
    int rg = tid >> 5, cg = tid & 31;
    int r0 = rg * 4, c0 = cg * 8;
    float acc[4][8];
#pragma unroll
    for (int i = 0; i < 4; ++i)
#pragma unroll
        for (int j = 0; j < 8; ++j) acc[i][j] = 0.f;

#pragma unroll 2
    for (int k = 0; k < DDIM; k += 4) {
        float a[4][4];
#pragma unroll
        for (int i = 0; i < 4; ++i) {
            float4 t = *(const float4*)&As[(r0 + i) * 132 + k];
            a[i][0] = t.x; a[i][1] = t.y; a[i][2] = t.z; a[i][3] = t.w;
        }
#pragma unroll
        for (int kk = 0; kk < 4; ++kk) {
            float4 w0 = *(const float4*)&W[(size_t)(k + kk) * HDIM + c0];
            float4 w1 = *(const float4*)&W[(size_t)(k + kk) * HDIM + c0 + 4];
            float wv[8] = {w0.x, w0.y, w0.z, w0.w, w1.x, w1.y, w1.z, w1.w};
#pragma unroll
            for (int i = 0; i < 4; ++i)
#pragma unroll
                for (int j = 0; j < 8; ++j) acc[i][j] += a[i][kk] * wv[j];
        }
    }
    float4 bz0 = *(const float4*)&bias[c0];
    float4 bz1 = *(const float4*)&bias[c0 + 4];
    float bz[8] = {bz0.x, bz0.y, bz0.z, bz0.w, bz1.x, bz1.y, bz1.z, bz1.w};
#pragma unroll
    for (int i = 0; i < 4; ++i) {
        float4 o0, o1;
        o0.x = acc[i][0] + bz[0]; o0.y = acc[i][1] + bz[1]; o0.z = acc[i][2] + bz[2]; o0.w = acc[i][3] + bz[3];
        o1.x = acc[i][4] + bz[4]; o1.y = acc[i][5] + bz[5]; o1.z = acc[i][6] + bz[6]; o1.w = acc[i][7] + bz[7];
        *(float4*)&out[(rowbase + r0 + i) * HDIM + c0] = o0;
        *(float4*)&out[(rowbase + r0 + i) * HDIM + c0 + 4] = o1;
    }
}

// ---------------- row L2-normalize (in place), 4 rows / block ----------------
__global__ void normalize_kernel(float* __restrict__ keys) {
    int tid = threadIdx.x;
    int lane = tid & 63, wv = tid >> 6;
    size_t row = (size_t)blockIdx.x * 4 + wv;
    float4* p = (float4*)&keys[row * HDIM + lane * 4];
    float4 v = *p;
    float ss = v.x * v.x + v.y * v.y + v.z * v.z + v.w * v.w;
#pragma unroll
    for (int m = 32; m; m >>= 1) ss += __shfl_xor(ss, m);
    float sc = 1.0f / fmaxf(sqrtf(ss), 1e-12f);
    v.x *= sc; v.y *= sc; v.z *= sc; v.w *= sc;
    *p = v;
}

// ---------------- gather top-8 rows + mean, 2 rows / block ----------------
__global__ void gather_mean_kernel(const float* __restrict__ state, const int* __restrict__ idx,
                                   float* __restrict__ M) {
    __shared__ int ilds[16];
    int tid = threadIdx.x;
    int row0 = blockIdx.x * 2;
    if (tid < 16) ilds[tid] = idx[(size_t)row0 * 8 + tid];
    __syncthreads();
    int lr = tid >> 7, d = tid & 127;
    int grow = row0 + lr;
    int b = grow >> 12;
    const float* sb = state + (size_t)b * NN * DDIM;
    float acc = 0.f;
#pragma unroll
    for (int k = 0; k < 8; ++k) acc += sb[(size_t)ilds[lr * 8 + k] * DDIM + d];
    M[(size_t)grow * DDIM + d] = acc * 0.125f;
}

// ---------------- concat GEMM (K=384) + LayerNorm epilogue ----------------
__global__ __launch_bounds__(256, 2)
void gemm_ln(const float* __restrict__ state, const float* __restrict__ agg,
             const float* __restrict__ W1, const float* __restrict__ b1,
             const float* __restrict__ lng, const float* __restrict__ lnb,
             float* __restrict__ h) {
    __shared__ float As[32 * 388];
    int tid = threadIdx.x;
    size_t rowbase = (size_t)blockIdx.x * 32;
    for (int i = tid; i < 32 * 96; i += 256) {
        int r = i / 96, q = i % 96;
        float4 v;
        if (q < 32) v = *(const float4*)&state[(rowbase + r) * DDIM + q * 4];
        else        v = *(const float4*)&agg[(rowbase + r) * HDIM + (q - 32) * 4];
        *(float4*)&As[r * 388 + q * 4] = v;
    }
    __syncthreads();
    int rg = tid >> 5, cg = tid & 31;
    int r0 = rg * 4, c0 = cg * 8;
    float acc[4][8];
#pragma unroll
    for (int i = 0; i < 4; ++i)
#pragma unroll
        for (int j = 0; j < 8; ++j) acc[i][j] = 0.f;

#pragma unroll 2
    for (int k = 0; k < 384; k += 4) {
        float a[4][4];
#pragma unroll
        for (int i = 0; i < 4; ++i) {
            float4 t = *(const float4*)&As[(r0 + i) * 388 + k];
            a[i][0] = t.x; a[i][1] = t.y; a[i][2] = t.z; a[i][3] = t.w;
        }
#pragma unroll
        for (int kk = 0; kk < 4; ++kk) {
            float4 w0 = *(const float4*)&W1[(size_t)(k + kk) * HDIM + c0];
            float4 w1 = *(const float4*)&W1[(size_t)(k + kk) * HDIM + c0 + 4];
            float wv[8] = {w0.x, w0.y, w0.z, w0.w, w1.x, w1.y, w1.z, w1.w};
#pragma unroll
            for (int i = 0; i < 4; ++i)
#pragma unroll
                for (int j = 0; j < 8; ++j) acc[i][j] += a[i][kk] * wv[j];
        }
    }
    // + bias, then LayerNorm over the 256 columns (32 lanes x 8 cols per row)
    float4 b10 = *(const float4*)&b1[c0];
    float4 b11 = *(const float4*)&b1[c0 + 4];
    float bb[8] = {b10.x, b10.y, b10.z, b10.w, b11.x, b11.y, b11.z, b11.w};
    float4 g0 = *(const float4*)&lng[c0];
    float4 g1 = *(const float4*)&lng[c0 + 4];
    float lg[8] = {g0.x, g0.y, g0.z, g0.w, g1.x, g1.y, g1.z, g1.w};
    float4 e0 = *(const float4*)&lnb[c0];
    float4 e1 = *(const float4*)&lnb[c0 + 4];
    float lb[8] = {e0.x, e0.y, e0.z, e0.w, e1.x, e1.y, e1.z, e1.w};

#pragma unroll
    for (int i = 0; i < 4; ++i) {
        float s1 = 0.f, s2 = 0.f;
#pragma unroll
        for (int j = 0; j < 8; ++j) {
            acc[i][j] += bb[j];
            s1 += acc[i][j];
            s2 += acc[i][j] * acc[i][j];
        }
#pragma unroll
        for (int m = 16; m; m >>= 1) { s1 += __shfl_xor(s1, m); s2 += __shfl_xor(s2, m); }
        float mu = s1 * (1.0f / HDIM);
        float var = s2 * (1.0f / HDIM) - mu * mu;
        float inv = 1.0f / sqrtf(var + 1e-5f);
        float4 o0, o1;
        o0.x = (acc[i][0] - mu) * inv * lg[0] + lb[0];
        o0.y = (acc[i][1] - mu) * inv * lg[1] + lb[1];
        o0.z = (acc[i][2] - mu) * inv * lg[2] + lb[2];
        o0.w = (acc[i][3] - mu) * inv * lg[3] + lb[3];
        o1.x = (acc[i][4] - mu) * inv * lg[4] + lb[4];
        o1.y = (acc[i][5] - mu) * inv * lg[5] + lb[5];
        o1.z = (acc[i][6] - mu) * inv * lg[6] + lb[6];
        o1.w = (acc[i][7] - mu) * inv * lg[7] + lb[7];
        *(float4*)&h[(rowbase + r0 + i) * HDIM + c0] = o0;
        *(float4*)&h[(rowbase + r0 + i) * HDIM + c0 + 4] = o1;
    }
}

// ---------------- update GEMM: state += silu(h) @ W2 + b2 ----------------
__global__ __launch_bounds__(256, 2)
void gemm_upd(const float* __restrict__ h, const float* __restrict__ W2,
              const float* __restrict__ b2, float* __restrict__ state) {
    __shared__ float As[32 * 260];
    int tid = threadIdx.x;
    size_t rowbase = (size_t)blockIdx.x * 32;
    for (int i = tid; i < 32 * 64; i += 256) {
        int r = i >> 6, q = i & 63;
        float4 v = *(const float4*)&h[(rowbase + r) * HDIM + q * 4];
        v.x = v.x / (1.0f + expf(-v.x));
        v.y = v.y / (1.0f + expf(-v.y));
        v.z = v.z / (1.0f + expf(-v.z));
        v.w = v.w / (1.0f + expf(-v.w));
        *(float4*)&As[r * 260 + q * 4] = v;
    }
    __syncthreads();
    int rg = tid >> 4, cg = tid & 15;
    int r0 = rg * 2, c0 = cg * 8;
    float acc[2][8];
#pragma unroll
    for (int i = 0; i < 2; ++i)
#pragma unroll
        for (int j = 0; j < 8; ++j) acc[i][j] = 0.f;

#pragma unroll 2
    for (int k = 0; k < HDIM; k += 4) {
        float a[2][4];
#pragma unroll
        for (int i = 0; i < 2; ++i) {
            float4 t = *(const float4*)&As[(r0 + i) * 260 + k];
            a[i][0] = t.x; a[i][1] = t.y; a[i][2] = t.z; a[i][3] = t.w;
        }
#pragma unroll
        for (int kk = 0; kk < 4; ++kk) {
            float4 w0 = *(const float4*)&W2[(size_t)(k + kk) * DDIM + c0];
            float4 w1 = *(const float4*)&W2[(size_t)(k + kk) * DDIM + c0 + 4];
            float wv[8] = {w0.x, w0.y, w0.z, w0.w, w1.x, w1.y, w1.z, w1.w};
#pragma unroll
            for (int i = 0; i < 2; ++i)
#pragma unroll
                for (int j = 0; j < 8; ++j) acc[i][j] += a[i][kk] * wv[j];
        }
    }
    float4 bz0 = *(const float4*)&b2[c0];
    float4 bz1 = *(const float4*)&b2[c0 + 4];
    float bz[8] = {bz0.x, bz0.y, bz0.z, bz0.w, bz1.x, bz1.y, bz1.z, bz1.w};
#pragma unroll
    for (int i = 0; i < 2; ++i) {
        size_t off = (rowbase + r0 + i) * DDIM + c0;
        float4 s0 = *(const float4*)&state[off];
        float4 s1 = *(const float4*)&state[off + 4];
        s0.x += acc[i][0] + bz[0]; s0.y += acc[i][1] + bz[1];
        s0.z += acc[i][2] + bz[2]; s0.w += acc[i][3] + bz[3];
        s1.x += acc[i][4] + bz[4]; s1.y += acc[i][5] + bz[5];
        s1.z += acc[i][6] + bz[6]; s1.w += acc[i][7] + bz[7];
        *(float4*)&state[off] = s0;
        *(float4*)&state[off + 4] = s1;
    }
}

// ---------------- final: mean over N, then @ Wo + bo ----------------
__global__ void partial_mean_kernel(const float* __restrict__ state, float* __restrict__ partial) {
    int b = blockIdx.y, seg = blockIdx.x, tid = threadIdx.x;  // 128 threads
    const float* sp = state + ((size_t)b * NN + (size_t)seg * 128) * DDIM;
    float acc = 0.f;
    for (int i = 0; i < 128; ++i) acc += sp[(size_t)i * DDIM + tid];
    partial[((size_t)b * 32 + seg) * DDIM + tid] = acc;
}

__global__ void final_out_kernel(const float* __restrict__ partial, const float* __restrict__ Wo,
                                 const float* __restrict__ bo, float* __restrict__ out) {
    __shared__ float mean[BQ][DDIM];
    int tid = threadIdx.x;
    for (int o = tid; o < BQ * DDIM; o += 256) {
        int b = o >> 7, d = o & 127;
        float s = 0.f;
        for (int p = 0; p < 32; ++p) s += partial[((size_t)b * 32 + p) * DDIM + d];
        mean[b][d] = s * (1.0f / NN);
    }
    __syncthreads();
    for (int o = tid; o < BQ * DDIM; o += 256) {
        int b = o >> 7, c = o & 127;
        float acc = bo[c];
        for (int d = 0; d < DDIM; ++d) acc += mean[b][d] * Wo[d * DDIM + c];
        out[o] = acc;
    }
}

extern "C" void kernel_launch(void* const* d_in, const int* in_sizes, int n_in,
                              void* d_out, int out_size, void* d_ws, size_t ws_size,
                              hipStream_t stream) {
    const float* x   = (const float*)d_in[0];
    const float* Wn  = (const float*)d_in[1];
    const float* bn  = (const float*)d_in[2];
    const float* W1  = (const float*)d_in[3];
    const float* b1  = (const float*)d_in[4];
    const float* lng = (const float*)d_in[5];
    const float* lnb = (const float*)d_in[6];
    const float* W2  = (const float*)d_in[7];
    const float* b2  = (const float*)d_in[8];
    const float* Wo  = (const float*)d_in[9];
    const float* bo  = (const float*)d_in[10];
    float* out = (float*)d_out;

    // workspace layout (floats): state | keysagg | hbuf(=Mbuf alias region) | partial | idx
    float* ws      = (float*)d_ws;
    float* state   = ws;                                   // R*128
    float* keysagg = state + (size_t)RTOT * DDIM;          // R*256 (keys, later agg)
    float* hbuf    = keysagg + (size_t)RTOT * HDIM;        // R*256 (h; its first R*128 also used as M)
    float* Mbuf    = hbuf;                                 // M dead before h is written
    float* partial = hbuf + (size_t)RTOT * HDIM;           // B*32*128
    int*   idxbuf  = (int*)(partial + (size_t)BQ * 32 * DDIM); // R*8 ints

    hipMemcpyAsync(state, x, (size_t)RTOT * DDIM * sizeof(float),
                   hipMemcpyDeviceToDevice, stream);

    (void)hipFuncSetAttribute((const void*)sim_topk_kernel,
                              hipFuncAttributeMaxDynamicSharedMemorySize,
                              2 * 64 * SA * 4);

    for (int step = 0; step < 3; ++step) {
        gemm_d_h<<<RTOT / 32, 256, 0, stream>>>(state, Wn, bn, keysagg);
        normalize_kernel<<<RTOT / 4, 256, 0, stream>>>(keysagg);
        sim_topk_kernel<<<256, 256, 2 * 64 * SA * 4, stream>>>(keysagg, idxbuf);
        gather_mean_kernel<<<RTOT / 2, 256, 0, stream>>>(state, idxbuf, Mbuf);
        gemm_d_h<<<RTOT / 32, 256, 0, stream>>>(Mbuf, Wn, bn, keysagg);
        gemm_ln<<<RTOT / 32, 256, 0, stream>>>(state, keysagg, W1, b1, lng, lnb, hbuf);
        gemm_upd<<<RTOT / 32, 256, 0, stream>>>(hbuf, W2, b2, state);
    }
    partial_mean_kernel<<<dim3(32, BQ), 128, 0, stream>>>(state, partial);
    final_out_kernel<<<1, 256, 0, stream>>>(partial, Wo, bo, out);
}

// Round 2
// 1437.401 us; speedup vs baseline: 2.6451x; 2.6451x over previous
//
#include <hip/hip_runtime.h>

#define DDIM 128
#define HDIM 256
#define BQ   4
#define NN   4096
#define RTOT (BQ*NN)

typedef short short8 __attribute__((ext_vector_type(8)));
typedef float f32x16 __attribute__((ext_vector_type(16)));

#define SIM_LDS_BYTES (3*32768 + 64*129*4)

__device__ inline unsigned short f2bf(float f) {
    unsigned int u = __float_as_uint(f);
    unsigned int r = (u + 0x7fffu + ((u >> 16) & 1u)) >> 16;
    return (unsigned short)r;
}
__device__ inline float bf2f(unsigned short h) {
    return __uint_as_float(((unsigned int)h) << 16);
}

// ---------------- fused sim (K K^T, split-bf16 MFMA) + per-row top-8 ----------------
// grid 256 (1 block/CU), block 256 (4 waves). Block = 64 rows x 4096 cols, chunked 128 cols.
// Wave = 32 rows x 64 cols (2 col-frags of 32x32). A (hi+lo) in registers, B staged in LDS
// (3 buffers x 32KB, kblock=64, 2-deep prefetch, counted vmcnt, XOR-swizzled 16B segments).
__global__ __launch_bounds__(256, 1)
void sim_topk_kernel(const unsigned short* __restrict__ khi,
                     const unsigned short* __restrict__ klo,
                     int* __restrict__ idxout) {
    extern __shared__ char smem[];
    float* dmp = (float*)(smem + 3*32768);   // [64][129] f32

    const int id = blockIdx.x;
    const int b = (id & 7) >> 1;                    // XCD-pair -> batch (L2 locality)
    const int tile = ((id >> 3) << 1) | (id & 1);
    const int rowbase = tile * 64;
    const unsigned short* khiB = khi + (size_t)b * NN * HDIM;
    const unsigned short* kloB = klo + (size_t)b * NN * HDIM;

    const int tid = threadIdx.x;
    const int lane = tid & 63, w = tid >> 6;
    const int rs = w >> 1, cs = w & 1;
    const int l31 = lane & 31, lh = lane >> 5;

    // ---- A fragments (this wave's 32 rows, full K=256, hi+lo) in registers ----
    short8 ah[16], al[16];
    {
        const unsigned short* pa = khiB + (size_t)(rowbase + rs*32 + l31) * HDIM + lh*8;
        const unsigned short* pl = kloB + (size_t)(rowbase + rs*32 + l31) * HDIM + lh*8;
#pragma unroll
        for (int t = 0; t < 16; ++t) {
            ah[t] = *(const short8*)(pa + t*16);
            al[t] = *(const short8*)(pl + t*16);
        }
    }

    // staging: wave w stages cols [32w,32w+32) of (chunk2,kb2) into buffer sel2.
    // LDS linear dest; global source pre-swizzled seg' = seg ^ (col&7)  (involution).
    const int srow_off = lane >> 3;                       // 0..7 (col within 8-col group)
    const int sseg = ((lane & 7) ^ (lane >> 3)) * 8;      // element offset of swizzled 16B seg
    auto stage = [&](int chunk2, int kb2, int sel2) {
        char* ldsb = smem + sel2 * 32768;
        const int colbase = chunk2 * 128;
#pragma unroll
        for (int q = 0; q < 4; ++q) {
            const int c0 = w*32 + q*8;
            const unsigned short* src = khiB + (size_t)(colbase + c0 + srow_off)*HDIM + kb2*64 + sseg;
            __builtin_amdgcn_global_load_lds(
                (const __attribute__((address_space(1))) void*)src,
                (__attribute__((address_space(3))) void*)(ldsb + c0*128), 16, 0, 0);
        }
#pragma unroll
        for (int q = 0; q < 4; ++q) {
            const int c0 = w*32 + q*8;
            const unsigned short* src = kloB + (size_t)(colbase + c0 + srow_off)*HDIM + kb2*64 + sseg;
            __builtin_amdgcn_global_load_lds(
                (const __attribute__((address_space(1))) void*)src,
                (__attribute__((address_space(3))) void*)(ldsb + 16384 + c0*128), 16, 0, 0);
        }
    };

    stage(0, 0, 0);
    stage(0, 1, 1);

    float tv[8]; int tix[8];
#pragma unroll
    for (int s = 0; s < 8; ++s) { tv[s] = -1e30f; tix[s] = 0x7fffffff; }
    const int srow = tid & 63, scq = tid >> 6;   // scan: row, col-quarter

    const int cA = cs*64 + l31;      // this lane's col (frag 0); frag 1 = +32
    const int xr = cA & 7;           // read-side swizzle key (same for both frags)

    for (int chunk = 0; chunk < 32; ++chunk) {
        f32x16 accA0, accB0, accA1, accB1;
#pragma unroll
        for (int r = 0; r < 16; ++r) { accA0[r]=0.f; accB0[r]=0.f; accA1[r]=0.f; accB1[r]=0.f; }

#pragma unroll
        for (int kb = 0; kb < 4; ++kb) {
            if (chunk*4 + kb < 127) asm volatile("s_waitcnt vmcnt(8)" ::: "memory");
            else                    asm volatile("s_waitcnt vmcnt(0)" ::: "memory");
            __builtin_amdgcn_s_barrier();
            __builtin_amdgcn_sched_barrier(0);
            if (chunk*4 + kb + 2 < 128) {                 // prefetch 2 kblocks ahead
                const int c2 = chunk + ((kb+2) >> 2);
                const int k2 = (kb+2) & 3;
                stage(c2, k2, (c2 + k2) % 3);
            }
            {
                char* bb = smem + ((chunk + kb) % 3) * 32768;
                const char* bh_base = bb + cA*128;
                const char* bl_base = bb + 16384 + cA*128;
#pragma unroll
                for (int kk = 0; kk < 4; ++kk) {
                    const int gk = kb*4 + kk;                    // static index into ah/al
                    const int so = ((kk*2 + lh) ^ xr) * 16;      // swizzled 16B segment
                    short8 bh0 = *(const short8*)(bh_base + so);
                    short8 bl0 = *(const short8*)(bl_base + so);
                    short8 bh1 = *(const short8*)(bh_base + 32*128 + so);
                    short8 bl1 = *(const short8*)(bl_base + 32*128 + so);
                    accA0 = __builtin_amdgcn_mfma_f32_32x32x16_bf16(ah[gk], bh0, accA0, 0, 0, 0);
                    accB0 = __builtin_amdgcn_mfma_f32_32x32x16_bf16(ah[gk], bl0, accB0, 0, 0, 0);
                    accA1 = __builtin_amdgcn_mfma_f32_32x32x16_bf16(ah[gk], bh1, accA1, 0, 0, 0);
                    accB1 = __builtin_amdgcn_mfma_f32_32x32x16_bf16(ah[gk], bl1, accB1, 0, 0, 0);
                    accB0 = __builtin_amdgcn_mfma_f32_32x32x16_bf16(al[gk], bh0, accB0, 0, 0, 0);
                    accB1 = __builtin_amdgcn_mfma_f32_32x32x16_bf16(al[gk], bh1, accB1, 0, 0, 0);
                }
            }
        }

        // dump 64x128 sim tile to LDS (C layout: col=lane&31, row=(r&3)+8*(r>>2)+4*(lane>>5))
#pragma unroll
        for (int r = 0; r < 16; ++r) {
            const int rr = rs*32 + 4*lh + (r & 3) + 8*(r >> 2);
            dmp[rr*129 + cs*64 + l31]      = accA0[r] + accB0[r];
            dmp[rr*129 + cs*64 + 32 + l31] = accA1[r] + accB1[r];
        }
        asm volatile("s_waitcnt lgkmcnt(0)" ::: "memory");
        __builtin_amdgcn_s_barrier();
        __builtin_amdgcn_sched_barrier(0);

        // running top-8: thread scans its 32 cols of its row, ascending (strict > = ref ties)
        {
            const float* rp = dmp + srow*129 + scq*32;
            const int colb = chunk*128 + scq*32;
#pragma unroll 4
            for (int i = 0; i < 32; ++i) {
                float v = rp[i];
                if (v > tv[7]) {
                    tv[7] = v; tix[7] = colb + i;
#pragma unroll
                    for (int s = 7; s >= 1; --s) {
                        if (tv[s] > tv[s-1]) {
                            float t0 = tv[s]; tv[s] = tv[s-1]; tv[s-1] = t0;
                            int  i0 = tix[s]; tix[s] = tix[s-1]; tix[s-1] = i0;
                        }
                    }
                }
            }
        }
    }

    // merge 4 partial lists per row (lexicographic: ties -> lowest index)
    __syncthreads();
    float* cv = dmp;                  // [64][32]
    int*   civ = (int*)(dmp + 64*32); // [64][32]
#pragma unroll
    for (int s = 0; s < 8; ++s) {
        cv[srow*32 + scq*8 + s] = tv[s];
        civ[srow*32 + scq*8 + s] = tix[s];
    }
    __syncthreads();
    if (tid < 64) {
        float fv[8]; int fi[8];
#pragma unroll
        for (int s = 0; s < 8; ++s) { fv[s] = -1e30f; fi[s] = 0x7fffffff; }
        for (int s2 = 0; s2 < 32; ++s2) {
            float v = cv[tid*32 + s2];
            int  ix = civ[tid*32 + s2];
            bool ins = (v > fv[7]) || (v == fv[7] && ix < fi[7]);
            if (ins) {
                fv[7] = v; fi[7] = ix;
#pragma unroll
                for (int t = 7; t >= 1; --t) {
                    bool sw = (fv[t] > fv[t-1]) || (fv[t] == fv[t-1] && fi[t] < fi[t-1]);
                    if (sw) {
                        float a0 = fv[t]; fv[t] = fv[t-1]; fv[t-1] = a0;
                        int   c0_ = fi[t]; fi[t] = fi[t-1]; fi[t-1] = c0_;
                    }
                }
            }
        }
        size_t basei = ((size_t)b*NN + rowbase + tid) * 8;
#pragma unroll
        for (int s = 0; s < 8; ++s) idxout[basei + s] = fi[s];
    }
}

// ---------------- keys projection GEMM + fused normalize -> khi/klo (bf16 planes) ----------------
// grid R/32, block 256
__global__ __launch_bounds__(256, 2)
void gemm_keys(const float* __restrict__ A, const float* __restrict__ W,
               const float* __restrict__ bias,
               unsigned short* __restrict__ khi, unsigned short* __restrict__ klo) {
    __shared__ float As[32 * 132];
    int tid = threadIdx.x;
    size_t rowbase = (size_t)blockIdx.x * 32;
    for (int i = tid; i < 32 * 32; i += 256) {
        int r = i >> 5, q = i & 31;
        *(float4*)&As[r * 132 + q * 4] = *(const float4*)&A[(rowbase + r) * DDIM + q * 4];
    }
    __syncthreads();
    int rg = tid >> 5, cg = tid & 31;
    int r0 = rg * 4, c0 = cg * 8;
    float acc[4][8];
#pragma unroll
    for (int i = 0; i < 4; ++i)
#pragma unroll
        for (int j = 0; j < 8; ++j) acc[i][j] = 0.f;

#pragma unroll 2
    for (int k = 0; k < DDIM; k += 4) {
        float a[4][4];
#pragma unroll
        for (int i = 0; i < 4; ++i) {
            float4 t = *(const float4*)&As[(r0 + i) * 132 + k];
            a[i][0] = t.x; a[i][1] = t.y; a[i][2] = t.z; a[i][3] = t.w;
        }
#pragma unroll
        for (int kk = 0; kk < 4; ++kk) {
            float4 w0 = *(const float4*)&W[(size_t)(k + kk) * HDIM + c0];
            float4 w1 = *(const float4*)&W[(size_t)(k + kk) * HDIM + c0 + 4];
            float wv[8] = {w0.x, w0.y, w0.z, w0.w, w1.x, w1.y, w1.z, w1.w};
#pragma unroll
            for (int i = 0; i < 4; ++i)
#pragma unroll
                for (int j = 0; j < 8; ++j) acc[i][j] += a[i][kk] * wv[j];
        }
    }
    float4 bz0 = *(const float4*)&bias[c0];
    float4 bz1 = *(const float4*)&bias[c0 + 4];
    float bz[8] = {bz0.x, bz0.y, bz0.z, bz0.w, bz1.x, bz1.y, bz1.z, bz1.w};
#pragma unroll
    for (int i = 0; i < 4; ++i) {
        float vv[8];
        float ss = 0.f;
#pragma unroll
        for (int j = 0; j < 8; ++j) { vv[j] = acc[i][j] + bz[j]; ss += vv[j]*vv[j]; }
#pragma unroll
        for (int m = 16; m; m >>= 1) ss += __shfl_xor(ss, m);
        float sc = 1.0f / fmaxf(sqrtf(ss), 1e-12f);
        short8 hv, lv;
#pragma unroll
        for (int j = 0; j < 8; ++j) {
            float vn = vv[j] * sc;
            unsigned short h = f2bf(vn);
            hv[j] = (short)h;
            lv[j] = (short)f2bf(vn - bf2f(h));
        }
        *(short8*)&khi[(rowbase + r0 + i) * HDIM + c0] = hv;
        *(short8*)&klo[(rowbase + r0 + i) * HDIM + c0] = lv;
    }
}

// ---------------- agg projection GEMM: out = A(Rx128) @ W(128x256) + bias ----------------
__global__ __launch_bounds__(256, 2)
void gemm_d_h(const float* __restrict__ A, const float* __restrict__ W,
              const float* __restrict__ bias, float* __restrict__ out) {
    __shared__ float As[32 * 132];
    int tid = threadIdx.x;
    size_t rowbase = (size_t)blockIdx.x * 32;
    for (int i = tid; i < 32 * 32; i += 256) {
        int r = i >> 5, q = i & 31;
        *(float4*)&As[r * 132 + q * 4] = *(const float4*)&A[(rowbase + r) * DDIM + q * 4];
    }
    __syncthreads();
    int rg = tid >> 5, cg = tid & 31;
    int r0 = rg * 4, c0 = cg * 8;
    float acc[4][8];
#pragma unroll
    for (int i = 0; i < 4; ++i)
#pragma unroll
        for (int j = 0; j < 8; ++j) acc[i][j] = 0.f;

#pragma unroll 2
    for (int k = 0; k < DDIM; k += 4) {
        float a[4][4];
#pragma unroll
        for (int i = 0; i < 4; ++i) {
            float4 t = *(const float4*)&As[(r0 + i) * 132 + k];
            a[i][0] = t.x; a[i][1] = t.y; a[i][2] = t.z; a[i][3] = t.w;
        }
#pragma unroll
        for (int kk = 0; kk < 4; ++kk) {
            float4 w0 = *(const float4*)&W[(size_t)(k + kk) * HDIM + c0];
            float4 w1 = *(const float4*)&W[(size_t)(k + kk) * HDIM + c0 + 4];
            float wv[8] = {w0.x, w0.y, w0.z, w0.w, w1.x, w1.y, w1.z, w1.w};
#pragma unroll
            for (int i = 0; i < 4; ++i)
#pragma unroll
                for (int j = 0; j < 8; ++j) acc[i][j] += a[i][kk] * wv[j];
        }
    }
    float4 bz0 = *(const float4*)&bias[c0];
    float4 bz1 = *(const float4*)&bias[c0 + 4];
    float bz[8] = {bz0.x, bz0.y, bz0.z, bz0.w, bz1.x, bz1.y, bz1.z, bz1.w};
#pragma unroll
    for (int i = 0; i < 4; ++i) {
        float4 o0, o1;
        o0.x = acc[i][0] + bz[0]; o0.y = acc[i][1] + bz[1]; o0.z = acc[i][2] + bz[2]; o0.w = acc[i][3] + bz[3];
        o1.x = acc[i][4] + bz[4]; o1.y = acc[i][5] + bz[5]; o1.z = acc[i][6] + bz[6]; o1.w = acc[i][7] + bz[7];
        *(float4*)&out[(rowbase + r0 + i) * HDIM + c0] = o0;
        *(float4*)&out[(rowbase + r0 + i) * HDIM + c0 + 4] = o1;
    }
}

// ---------------- gather top-8 rows + mean, 2 rows / block ----------------
__global__ void gather_mean_kernel(const float* __restrict__ state, const int* __restrict__ idx,
                                   float* __restrict__ M) {
    __shared__ int ilds[16];
    int tid = threadIdx.x;
    int row0 = blockIdx.x * 2;
    if (tid < 16) ilds[tid] = idx[(size_t)row0 * 8 + tid];
    __syncthreads();
    int lr = tid >> 7, d = tid & 127;
    int grow = row0 + lr;
    int b = grow >> 12;
    const float* sb = state + (size_t)b * NN * DDIM;
    float acc = 0.f;
#pragma unroll
    for (int k = 0; k < 8; ++k) acc += sb[(size_t)ilds[lr * 8 + k] * DDIM + d];
    M[(size_t)grow * DDIM + d] = acc * 0.125f;
}

// ---------------- concat GEMM (K=384) + LayerNorm epilogue ----------------
__global__ __launch_bounds__(256, 2)
void gemm_ln(const float* __restrict__ state, const float* __restrict__ agg,
             const float* __restrict__ W1, const float* __restrict__ b1,
             const float* __restrict__ lng, const float* __restrict__ lnb,
             float* __restrict__ h) {
    __shared__ float As[32 * 388];
    int tid = threadIdx.x;
    size_t rowbase = (size_t)blockIdx.x * 32;
    for (int i = tid; i < 32 * 96; i += 256) {
        int r = i / 96, q = i % 96;
        float4 v;
        if (q < 32) v = *(const float4*)&state[(rowbase + r) * DDIM + q * 4];
        else        v = *(const float4*)&agg[(rowbase + r) * HDIM + (q - 32) * 4];
        *(float4*)&As[r * 388 + q * 4] = v;
    }
    __syncthreads();
    int rg = tid >> 5, cg = tid & 31;
    int r0 = rg * 4, c0 = cg * 8;
    float acc[4][8];
#pragma unroll
    for (int i = 0; i < 4; ++i)
#pragma unroll
        for (int j = 0; j < 8; ++j) acc[i][j] = 0.f;

#pragma unroll 2
    for (int k = 0; k < 384; k += 4) {
        float a[4][4];
#pragma unroll
        for (int i = 0; i < 4; ++i) {
            float4 t = *(const float4*)&As[(r0 + i) * 388 + k];
            a[i][0] = t.x; a[i][1] = t.y; a[i][2] = t.z; a[i][3] = t.w;
        }
#pragma unroll
        for (int kk = 0; kk < 4; ++kk) {
            float4 w0 = *(const float4*)&W1[(size_t)(k + kk) * HDIM + c0];
            float4 w1 = *(const float4*)&W1[(size_t)(k + kk) * HDIM + c0 + 4];
            float wv[8] = {w0.x, w0.y, w0.z, w0.w, w1.x, w1.y, w1.z, w1.w};
#pragma unroll
            for (int i = 0; i < 4; ++i)
#pragma unroll
                for (int j = 0; j < 8; ++j) acc[i][j] += a[i][kk] * wv[j];
        }
    }
    float4 b10 = *(const float4*)&b1[c0];
    float4 b11 = *(const float4*)&b1[c0 + 4];
    float bb[8] = {b10.x, b10.y, b10.z, b10.w, b11.x, b11.y, b11.z, b11.w};
    float4 g0 = *(const float4*)&lng[c0];
    float4 g1 = *(const float4*)&lng[c0 + 4];
    float lg[8] = {g0.x, g0.y, g0.z, g0.w, g1.x, g1.y, g1.z, g1.w};
    float4 e0 = *(const float4*)&lnb[c0];
    float4 e1 = *(const float4*)&lnb[c0 + 4];
    float lb[8] = {e0.x, e0.y, e0.z, e0.w, e1.x, e1.y, e1.z, e1.w};

#pragma unroll
    for (int i = 0; i < 4; ++i) {
        float s1 = 0.f, s2 = 0.f;
#pragma unroll
        for (int j = 0; j < 8; ++j) {
            acc[i][j] += bb[j];
            s1 += acc[i][j];
            s2 += acc[i][j] * acc[i][j];
        }
#pragma unroll
        for (int m = 16; m; m >>= 1) { s1 += __shfl_xor(s1, m); s2 += __shfl_xor(s2, m); }
        float mu = s1 * (1.0f / HDIM);
        float var = s2 * (1.0f / HDIM) - mu * mu;
        float inv = 1.0f / sqrtf(var + 1e-5f);
        float4 o0, o1;
        o0.x = (acc[i][0] - mu) * inv * lg[0] + lb[0];
        o0.y = (acc[i][1] - mu) * inv * lg[1] + lb[1];
        o0.z = (acc[i][2] - mu) * inv * lg[2] + lb[2];
        o0.w = (acc[i][3] - mu) * inv * lg[3] + lb[3];
        o1.x = (acc[i][4] - mu) * inv * lg[4] + lb[4];
        o1.y = (acc[i][5] - mu) * inv * lg[5] + lb[5];
        o1.z = (acc[i][6] - mu) * inv * lg[6] + lb[6];
        o1.w = (acc[i][7] - mu) * inv * lg[7] + lb[7];
        *(float4*)&h[(rowbase + r0 + i) * HDIM + c0] = o0;
        *(float4*)&h[(rowbase + r0 + i) * HDIM + c0 + 4] = o1;
    }
}

// ---------------- update GEMM: state += silu(h) @ W2 + b2 ----------------
__global__ __launch_bounds__(256, 2)
void gemm_upd(const float* __restrict__ h, const float* __restrict__ W2,
              const float* __restrict__ b2, float* __restrict__ state) {
    __shared__ float As[32 * 260];
    int tid = threadIdx.x;
    size_t rowbase = (size_t)blockIdx.x * 32;
    for (int i = tid; i < 32 * 64; i += 256) {
        int r = i >> 6, q = i & 63;
        float4 v = *(const float4*)&h[(rowbase + r) * HDIM + q * 4];
        v.x = v.x / (1.0f + expf(-v.x));
        v.y = v.y / (1.0f + expf(-v.y));
        v.z = v.z / (1.0f + expf(-v.z));
        v.w = v.w / (1.0f + expf(-v.w));
        *(float4*)&As[r * 260 + q * 4] = v;
    }
    __syncthreads();
    int rg = tid >> 4, cg = tid & 15;
    int r0 = rg * 2, c0 = cg * 8;
    float acc[2][8];
#pragma unroll
    for (int i = 0; i < 2; ++i)
#pragma unroll
        for (int j = 0; j < 8; ++j) acc[i][j] = 0.f;

#pragma unroll 2
    for (int k = 0; k < HDIM; k += 4) {
        float a[2][4];
#pragma unroll
        for (int i = 0; i < 2; ++i) {
            float4 t = *(const float4*)&As[(r0 + i) * 260 + k];
            a[i][0] = t.x; a[i][1] = t.y; a[i][2] = t.z; a[i][3] = t.w;
        }
#pragma unroll
        for (int kk = 0; kk < 4; ++kk) {
            float4 w0 = *(const float4*)&W2[(size_t)(k + kk) * DDIM + c0];
            float4 w1 = *(const float4*)&W2[(size_t)(k + kk) * DDIM + c0 + 4];
            float wv[8] = {w0.x, w0.y, w0.z, w0.w, w1.x, w1.y, w1.z, w1.w};
#pragma unroll
            for (int i = 0; i < 2; ++i)
#pragma unroll
                for (int j = 0; j < 8; ++j) acc[i][j] += a[i][kk] * wv[j];
        }
    }
    float4 bz0 = *(const float4*)&b2[c0];
    float4 bz1 = *(const float4*)&b2[c0 + 4];
    float bz[8] = {bz0.x, bz0.y, bz0.z, bz0.w, bz1.x, bz1.y, bz1.z, bz1.w};
#pragma unroll
    for (int i = 0; i < 2; ++i) {
        size_t off = (rowbase + r0 + i) * DDIM + c0;
        float4 s0 = *(const float4*)&state[off];
        float4 s1 = *(const float4*)&state[off + 4];
        s0.x += acc[i][0] + bz[0]; s0.y += acc[i][1] + bz[1];
        s0.z += acc[i][2] + bz[2]; s0.w += acc[i][3] + bz[3];
        s1.x += acc[i][4] + bz[4]; s1.y += acc[i][5] + bz[5];
        s1.z += acc[i][6] + bz[6]; s1.w += acc[i][7] + bz[7];
        *(float4*)&state[off] = s0;
        *(float4*)&state[off + 4] = s1;
    }
}

// ---------------- final: mean over N, then @ Wo + bo ----------------
__global__ void partial_mean_kernel(const float* __restrict__ state, float* __restrict__ partial) {
    int b = blockIdx.y, seg = blockIdx.x, tid = threadIdx.x;  // 128 threads
    const float* sp = state + ((size_t)b * NN + (size_t)seg * 128) * DDIM;
    float acc = 0.f;
    for (int i = 0; i < 128; ++i) acc += sp[(size_t)i * DDIM + tid];
    partial[((size_t)b * 32 + seg) * DDIM + tid] = acc;
}

__global__ void final_out_kernel(const float* __restrict__ partial, const float* __restrict__ Wo,
                                 const float* __restrict__ bo, float* __restrict__ out) {
    __shared__ float mean[BQ][DDIM];
    int tid = threadIdx.x;
    for (int o = tid; o < BQ * DDIM; o += 256) {
        int b = o >> 7, d = o & 127;
        float s = 0.f;
        for (int p = 0; p < 32; ++p) s += partial[((size_t)b * 32 + p) * DDIM + d];
        mean[b][d] = s * (1.0f / NN);
    }
    __syncthreads();
    for (int o = tid; o < BQ * DDIM; o += 256) {
        int b = o >> 7, c = o & 127;
        float acc = bo[c];
        for (int d = 0; d < DDIM; ++d) acc += mean[b][d] * Wo[d * DDIM + c];
        out[o] = acc;
    }
}

extern "C" void kernel_launch(void* const* d_in, const int* in_sizes, int n_in,
                              void* d_out, int out_size, void* d_ws, size_t ws_size,
                              hipStream_t stream) {
    const float* x   = (const float*)d_in[0];
    const float* Wn  = (const float*)d_in[1];
    const float* bn  = (const float*)d_in[2];
    const float* W1  = (const float*)d_in[3];
    const float* b1  = (const float*)d_in[4];
    const float* lng = (const float*)d_in[5];
    const float* lnb = (const float*)d_in[6];
    const float* W2  = (const float*)d_in[7];
    const float* b2  = (const float*)d_in[8];
    const float* Wo  = (const float*)d_in[9];
    const float* bo  = (const float*)d_in[10];
    float* out = (float*)d_out;

    // ws layout (floats): state | keysagg | hbuf | partial | idx
    // khi/klo (bf16) alias hbuf (dead until gemm_ln); Mbuf aliases khi region (dead after sim).
    float* ws      = (float*)d_ws;
    float* state   = ws;                                        // R*128 f32
    float* keysagg = state + (size_t)RTOT * DDIM;               // R*256 f32
    float* hbuf    = keysagg + (size_t)RTOT * HDIM;             // R*256 f32
    unsigned short* khi_b = (unsigned short*)hbuf;              // R*256 bf16
    unsigned short* klo_b = khi_b + (size_t)RTOT * HDIM;        // R*256 bf16
    float* Mbuf    = hbuf;                                      // R*128 f32 (after sim)
    float* partial = hbuf + (size_t)RTOT * HDIM;                // B*32*128
    int*   idxbuf  = (int*)(partial + (size_t)BQ * 32 * DDIM);  // R*8 ints

    hipMemcpyAsync(state, x, (size_t)RTOT * DDIM * sizeof(float),
                   hipMemcpyDeviceToDevice, stream);

    (void)hipFuncSetAttribute((const void*)sim_topk_kernel,
                              hipFuncAttributeMaxDynamicSharedMemorySize,
                              SIM_LDS_BYTES);

    for (int step = 0; step < 3; ++step) {
        gemm_keys<<<RTOT / 32, 256, 0, stream>>>(state, Wn, bn, khi_b, klo_b);
        sim_topk_kernel<<<256, 256, SIM_LDS_BYTES, stream>>>(khi_b, klo_b, idxbuf);
        gather_mean_kernel<<<RTOT / 2, 256, 0, stream>>>(state, idxbuf, Mbuf);
        gemm_d_h<<<RTOT / 32, 256, 0, stream>>>(Mbuf, Wn, bn, keysagg);
        gemm_ln<<<RTOT / 32, 256, 0, stream>>>(state, keysagg, W1, b1, lng, lnb, hbuf);
        gemm_upd<<<RTOT / 32, 256, 0, stream>>>(hbuf, W2, b2, state);
    }
    partial_mean_kernel<<<dim3(32, BQ), 128, 0, stream>>>(state, partial);
    final_out_kernel<<<1, 256, 0, stream>>>(partial, Wo, bo, out);
}